// Round 1
// baseline (4061.164 us; speedup 1.0000x reference)
//
#include <hip/hip_runtime.h>

// HeteroGNN baseline: f32 everywhere, atomics for scatter, register-tiled f32 GEMM.
// N=100000 nodes/type, E=500000 edges/relation, D_IN=D_HID=128, D_OUT=64.
//
// ws layout (floats): [0,3N): cnt_ll/cnt_pp/cnt_lp (-> dinv_ll/dinv_pp/invcnt)
//   [4N, 4N+640N): agg_ll, agg_pp, agg_lp, h_l, h_p (each N*128)
//   layer-2 temps t_l/u/v/wp (each N*64) alias the agg region after layer 1.
// Peak ws = 644*N*4B ~ 258 MB. Branches j,b run sequentially reusing buffers.

namespace {

constexpr int NN = 100000;
constexpr int EE = 500000;

__global__ __launch_bounds__(256) void zero_k(float* __restrict__ p, int n) {
  int i = blockIdx.x * 256 + threadIdx.x;
  if (i < n) p[i] = 0.f;
}

__global__ __launch_bounds__(256) void count_k(const int* __restrict__ col,
                                               float* __restrict__ cnt, int E) {
  int i = blockIdx.x * 256 + threadIdx.x;
  if (i < E) atomicAdd(&cnt[col[i]], 1.0f);
}

// in-place: cnt -> normalizers. GCN deg includes the self loop (+1).
__global__ __launch_bounds__(256) void make_inv_k(float* __restrict__ dll,
                                                  float* __restrict__ dpp,
                                                  float* __restrict__ ic, int n) {
  int i = blockIdx.x * 256 + threadIdx.x;
  if (i < n) {
    dll[i] = rsqrtf(dll[i] + 1.0f);
    dpp[i] = rsqrtf(dpp[i] + 1.0f);
    ic[i]  = 1.0f / fmaxf(ic[i], 1.0f);
  }
}

// agg_ll = dinv_ll^2 * x_l (self loop), agg_pp = dinv_pp^2 * x_p, agg_lp = 0
__global__ __launch_bounds__(256) void init_agg_k(
    const float* __restrict__ xl, const float* __restrict__ xp,
    const float* __restrict__ dll, const float* __restrict__ dpp,
    float* __restrict__ all_, float* __restrict__ app, float* __restrict__ alp,
    int n128) {
  int idx = blockIdx.x * 256 + threadIdx.x;
  if (idx < n128) {
    int i = idx >> 7;
    float a = dll[i], b = dpp[i];
    all_[idx] = a * a * xl[idx];
    app[idx]  = b * b * xp[idx];
    alp[idx]  = 0.f;
  }
}

// GCN edge scatter: out[c*ldc+d] += dinv[r]*dinv[c] * x[r*DD+d]
template <int DD>
__global__ __launch_bounds__(256) void gcn_scatter_k(
    const float* __restrict__ x, const float* __restrict__ dinv,
    const int* __restrict__ row, const int* __restrict__ col,
    float* __restrict__ out, int ldc, int E) {
  constexpr int EPB = 256 / DD;
  int e = blockIdx.x * EPB + threadIdx.x / DD;
  int d = threadIdx.x & (DD - 1);
  if (e < E) {
    int r = row[e], c = col[e];
    float nrm = dinv[r] * dinv[c];
    atomicAdd(&out[c * ldc + d], nrm * x[r * DD + d]);
  }
}

// plain / dst-scaled edge scatter (SAGE sum / mean)
template <int DD, bool SCALED>
__global__ __launch_bounds__(256) void sum_scatter_k(
    const float* __restrict__ x, const float* __restrict__ sc,
    const int* __restrict__ row, const int* __restrict__ col,
    float* __restrict__ out, int ldc, int E) {
  constexpr int EPB = 256 / DD;
  int e = blockIdx.x * EPB + threadIdx.x / DD;
  int d = threadIdx.x & (DD - 1);
  if (e < E) {
    int r = row[e], c = col[e];
    float v = x[r * DD + d];
    if (SCALED) v *= sc[c];
    atomicAdd(&out[c * ldc + d], v);
  }
}

// C[n,OC] = (ACCUM ? C : 0) + (rowscale? diag(rs):I) * A[n,128] @ W[128,OC] (+bias) (relu?)
// 256 threads, 128-row x OC-col tile, 8x(OC/16) per-thread register tile.
#define KC 32
#define BM 128
template <int OC, bool ACCUM, bool RELU, bool ROWSCALE>
__global__ __launch_bounds__(256) void gemm_k(
    const float* __restrict__ A, const float* __restrict__ W,
    const float* __restrict__ bias, const float* __restrict__ rowscale,
    float* __restrict__ C, int n) {
  constexpr int TN = (OC == 128) ? 8 : 4;
  __shared__ float As[KC][BM + 4];  // transposed chunk, padded
  __shared__ float Ws[KC][OC];

  const int tid = threadIdx.x;
  const int tr = tid >> 4;   // 0..15 row group
  const int tc = tid & 15;   // 0..15 col group
  const int row0 = blockIdx.x * BM;

  float acc[8][TN];
#pragma unroll
  for (int i = 0; i < 8; ++i)
#pragma unroll
    for (int j = 0; j < TN; ++j) acc[i][j] = 0.f;

  for (int kc = 0; kc < 128; kc += KC) {
    // stage A (transposed): thread loads A[row0+rr+8p][kc + kk]
    {
      int kk = tid & 31;
      int rr = tid >> 5;  // 0..7
#pragma unroll
      for (int p = 0; p < 16; ++p) {
        int r = rr + p * 8;
        int gr = row0 + r;
        float v = 0.f;
        if (gr < n) {
          v = A[gr * 128 + kc + kk];
          if (ROWSCALE) v *= rowscale[gr];
        }
        As[kk][r] = v;
      }
    }
    // stage W chunk
    for (int idx = tid; idx < KC * OC; idx += 256) {
      int kk = idx / OC, c = idx % OC;
      Ws[kk][c] = W[(kc + kk) * OC + c];
    }
    __syncthreads();

#pragma unroll
    for (int k = 0; k < KC; ++k) {
      float4 a0 = *reinterpret_cast<const float4*>(&As[k][tr * 8]);
      float4 a1 = *reinterpret_cast<const float4*>(&As[k][tr * 8 + 4]);
      float a[8] = {a0.x, a0.y, a0.z, a0.w, a1.x, a1.y, a1.z, a1.w};
      float w[TN];
      if (TN == 8) {
        float4 w0 = *reinterpret_cast<const float4*>(&Ws[k][tc * TN]);
        float4 w1 = *reinterpret_cast<const float4*>(&Ws[k][tc * TN + 4]);
        w[0] = w0.x; w[1] = w0.y; w[2] = w0.z; w[3] = w0.w;
        w[4] = w1.x; w[5] = w1.y; w[6] = w1.z; w[7] = w1.w;
      } else {
        float4 w0 = *reinterpret_cast<const float4*>(&Ws[k][tc * TN]);
        w[0] = w0.x; w[1] = w0.y; w[2] = w0.z; w[3] = w0.w;
      }
#pragma unroll
      for (int i = 0; i < 8; ++i)
#pragma unroll
        for (int j = 0; j < TN; ++j) acc[i][j] += a[i] * w[j];
    }
    __syncthreads();
  }

#pragma unroll
  for (int i = 0; i < 8; ++i) {
    int gr = row0 + tr * 8 + i;
    if (gr < n) {
#pragma unroll
      for (int j = 0; j < TN; ++j) {
        int c = tc * TN + j;
        float v = acc[i][j];
        if (bias) v += bias[c];
        if (ACCUM) v += C[gr * OC + c];
        if (RELU) v = fmaxf(v, 0.f);
        C[gr * OC + c] = v;
      }
    }
  }
}

// out_l[i*128+d] = dinv_ll[i]^2*t_l[i*64+d] + ll2_b[d]
// out_p[i*128+d] = v[i*64+d] + dinv_pp[i]^2*wp[i*64+d] + s2_bl[d] + pp2_b[d]
__global__ __launch_bounds__(256) void init_out_k(
    const float* __restrict__ t_l, const float* __restrict__ v_,
    const float* __restrict__ wp, const float* __restrict__ dll,
    const float* __restrict__ dpp, const float* __restrict__ ll2_b,
    const float* __restrict__ s2_bl, const float* __restrict__ pp2_b,
    float* __restrict__ out_l, float* __restrict__ out_p, int n64) {
  int idx = blockIdx.x * 256 + threadIdx.x;
  if (idx < n64) {
    int i = idx >> 6, d = idx & 63;
    float a = dll[i], b = dpp[i];
    out_l[i * 128 + d] = a * a * t_l[idx] + ll2_b[d];
    out_p[i * 128 + d] = v_[idx] + b * b * wp[idx] + s2_bl[d] + pp2_b[d];
  }
}

}  // namespace

extern "C" void kernel_launch(void* const* d_in, const int* in_sizes, int n_in,
                              void* d_out, int out_size, void* d_ws, size_t ws_size,
                              hipStream_t stream) {
  const size_t N = NN;
  const int E = EE;
  float* ws = (float*)d_ws;

  float* cnt_ll = ws;            // -> dinv_ll
  float* cnt_pp = ws + N;        // -> dinv_pp
  float* cnt_lp = ws + 2 * N;    // -> invcnt
  float* agg    = ws + 4 * N;
  float* agg_ll = agg;
  float* agg_pp = agg + 128 * N;
  float* agg_lp = agg + 256 * N;
  float* h_l    = agg + 384 * N;
  float* h_p    = agg + 512 * N;
  // layer-2 temps alias the (consumed) agg region
  float* t_l = agg;
  float* u_  = agg + 64 * N;
  float* v_  = agg + 128 * N;
  float* wp_ = agg + 192 * N;

  const int GRID_GEMM = (NN + BM - 1) / BM;          // 782
  const int GRID_E    = (E + 255) / 256;             // count kernels
  const int GRID_N    = (NN + 255) / 256;
  const int GRID_N128 = (NN * 128 + 255) / 256;      // 50000
  const int GRID_N64  = (NN * 64 + 255) / 256;       // 25000
  const int GRID_S128 = (E + 1) / 2;                 // 2 edges/block
  const int GRID_S64  = (E + 3) / 4;                 // 4 edges/block

  for (int g = 0; g < 2; ++g) {
    const int b = g * 19;
    const float* x_l   = (const float*)d_in[b + 0];
    const float* x_p   = (const float*)d_in[b + 1];
    const int*   ei_lp = (const int*)d_in[b + 2];
    const int*   ei_ll = (const int*)d_in[b + 3];
    const int*   ei_pp = (const int*)d_in[b + 4];
    const float* s1_wl = (const float*)d_in[b + 5];
    const float* s1_bl = (const float*)d_in[b + 6];
    const float* s1_wr = (const float*)d_in[b + 7];
    const float* ll1_w = (const float*)d_in[b + 8];
    const float* ll1_b = (const float*)d_in[b + 9];
    const float* pp1_w = (const float*)d_in[b + 10];
    const float* pp1_b = (const float*)d_in[b + 11];
    const float* s2_wl = (const float*)d_in[b + 12];
    const float* s2_bl = (const float*)d_in[b + 13];
    const float* s2_wr = (const float*)d_in[b + 14];
    const float* ll2_w = (const float*)d_in[b + 15];
    const float* ll2_b = (const float*)d_in[b + 16];
    const float* pp2_w = (const float*)d_in[b + 17];
    const float* pp2_b = (const float*)d_in[b + 18];
    float* out_l = (float*)d_out + g * 64;
    float* out_p = (float*)d_out + 128 * N + g * 64;

    // --- degrees ---
    zero_k<<<(3 * NN + 255) / 256, 256, 0, stream>>>(cnt_ll, 3 * NN);
    count_k<<<GRID_E, 256, 0, stream>>>(ei_ll + E, cnt_ll, E);
    count_k<<<GRID_E, 256, 0, stream>>>(ei_pp + E, cnt_pp, E);
    count_k<<<GRID_E, 256, 0, stream>>>(ei_lp + E, cnt_lp, E);
    make_inv_k<<<GRID_N, 256, 0, stream>>>(cnt_ll, cnt_pp, cnt_lp, NN);

    // --- layer 1 aggregation (on 128-dim inputs) ---
    init_agg_k<<<GRID_N128, 256, 0, stream>>>(x_l, x_p, cnt_ll, cnt_pp,
                                              agg_ll, agg_pp, agg_lp, NN * 128);
    gcn_scatter_k<128><<<GRID_S128, 256, 0, stream>>>(x_l, cnt_ll, ei_ll, ei_ll + E,
                                                      agg_ll, 128, E);
    gcn_scatter_k<128><<<GRID_S128, 256, 0, stream>>>(x_p, cnt_pp, ei_pp, ei_pp + E,
                                                      agg_pp, 128, E);
    sum_scatter_k<128, false><<<GRID_S128, 256, 0, stream>>>(x_l, nullptr, ei_lp,
                                                             ei_lp + E, agg_lp, 128, E);

    // --- layer 1 matmuls ---
    // h_l = relu(agg_ll @ ll1_w + ll1_b)
    gemm_k<128, false, true, false><<<GRID_GEMM, 256, 0, stream>>>(
        agg_ll, ll1_w, ll1_b, nullptr, h_l, NN);
    // h_p = relu((agg_lp*invcnt) @ s1_wl + s1_bl + x_p @ s1_wr + agg_pp @ pp1_w + pp1_b)
    gemm_k<128, false, false, true><<<GRID_GEMM, 256, 0, stream>>>(
        agg_lp, s1_wl, s1_bl, cnt_lp, h_p, NN);
    gemm_k<128, true, false, false><<<GRID_GEMM, 256, 0, stream>>>(
        x_p, s1_wr, pp1_b, nullptr, h_p, NN);
    gemm_k<128, true, true, false><<<GRID_GEMM, 256, 0, stream>>>(
        agg_pp, pp1_w, nullptr, nullptr, h_p, NN);

    // --- layer 2 matmuls first (project to 64), then aggregate ---
    gemm_k<64, false, false, false><<<GRID_GEMM, 256, 0, stream>>>(
        h_l, ll2_w, nullptr, nullptr, t_l, NN);
    gemm_k<64, false, false, false><<<GRID_GEMM, 256, 0, stream>>>(
        h_l, s2_wl, nullptr, nullptr, u_, NN);
    gemm_k<64, false, false, false><<<GRID_GEMM, 256, 0, stream>>>(
        h_p, s2_wr, nullptr, nullptr, v_, NN);
    gemm_k<64, false, false, false><<<GRID_GEMM, 256, 0, stream>>>(
        h_p, pp2_w, nullptr, nullptr, wp_, NN);

    // --- output init (biases + self loops + SAGE dst term), then edge scatters ---
    init_out_k<<<GRID_N64, 256, 0, stream>>>(t_l, v_, wp_, cnt_ll, cnt_pp,
                                             ll2_b, s2_bl, pp2_b, out_l, out_p,
                                             NN * 64);
    gcn_scatter_k<64><<<GRID_S64, 256, 0, stream>>>(t_l, cnt_ll, ei_ll, ei_ll + E,
                                                    out_l, 128, E);
    gcn_scatter_k<64><<<GRID_S64, 256, 0, stream>>>(wp_, cnt_pp, ei_pp, ei_pp + E,
                                                    out_p, 128, E);
    sum_scatter_k<64, true><<<GRID_S64, 256, 0, stream>>>(u_, cnt_lp, ei_lp,
                                                          ei_lp + E, out_p, 128, E);
  }
  (void)in_sizes; (void)n_in; (void)out_size; (void)ws_size;
}

// Round 3
// 3508.342 us; speedup vs baseline: 1.1576x; 1.1576x over previous
//
#include <hip/hip_runtime.h>

// HeteroGNN r1 (resubmit after infra timeout): CSR-based gather aggregation
// (no f32 atomics), f32 register GEMM.
// N=100000, E=500000, D_IN=D_HID=128, D_OUT=64.
//
// ws layout (32-bit words):
//   icnt   [0, 3N)           int   per-relation dst degree counts (ll|pp|lp)
//   offs   [3N, 6N+1)        int   exclusive scan of icnt (global positions), offs[3N]=3E
//   cur    [6N+4, 9N+4)      int   placement cursors (copy of offs)
//   bsum   [9N+4, 9N+516)    int   scan block sums
//   dinv   [9N+520, 12N+520) f32   dll | dpp | ic
//   srcs   [12N+520, 12N+520+3E) int  CSR src-node ids (global positions)
//   floats at FB = 12N + 520 + 3E (word-aligned to 4):
//     buf0 [FB, FB+128N)   buf1 [FB+128N, FB+256N)
//     h_l  [FB+256N, ...)  h_p  [FB+384N, FB+512N)
// Total ~ (12N+3E+512N)*4B ~ 216 MB.

namespace {

constexpr int NN = 100000;
constexpr int EE = 500000;

__global__ __launch_bounds__(256) void zero_int_k(int* __restrict__ p, int n) {
  int i = blockIdx.x * 256 + threadIdx.x;
  if (i < n) p[i] = 0;
}

__global__ __launch_bounds__(256) void count_int_k(const int* __restrict__ col,
                                                   int* __restrict__ cnt, int E) {
  int i = blockIdx.x * 256 + threadIdx.x;
  if (i < E) atomicAdd(&cnt[col[i]], 1);
}

__global__ __launch_bounds__(256) void make_inv_k(
    const int* __restrict__ cll, const int* __restrict__ cpp,
    const int* __restrict__ clp, float* __restrict__ dll,
    float* __restrict__ dpp, float* __restrict__ ic, int n) {
  int i = blockIdx.x * 256 + threadIdx.x;
  if (i < n) {
    dll[i] = rsqrtf((float)cll[i] + 1.0f);
    dpp[i] = rsqrtf((float)cpp[i] + 1.0f);
    ic[i]  = 1.0f / fmaxf((float)clp[i], 1.0f);
  }
}

// ---- 3-kernel exclusive scan over n ints (1024 elems / block) ----
__global__ __launch_bounds__(256) void scan1_k(const int* __restrict__ cnt,
                                               int* __restrict__ offs,
                                               int* __restrict__ bsum, int n) {
  __shared__ int ts[256];
  int tid = threadIdx.x;
  int base = blockIdx.x * 1024 + tid * 4;
  int v[4];
#pragma unroll
  for (int i = 0; i < 4; ++i) v[i] = (base + i < n) ? cnt[base + i] : 0;
  int s = v[0] + v[1] + v[2] + v[3];
  ts[tid] = s;
  __syncthreads();
  for (int off = 1; off < 256; off <<= 1) {
    int t = (tid >= off) ? ts[tid - off] : 0;
    __syncthreads();
    ts[tid] += t;
    __syncthreads();
  }
  int run = ts[tid] - s;  // thread-exclusive
#pragma unroll
  for (int i = 0; i < 4; ++i) {
    if (base + i < n) offs[base + i] = run;
    run += v[i];
  }
  if (tid == 255) bsum[blockIdx.x] = ts[255];
}

__global__ __launch_bounds__(512) void scan2_k(int* __restrict__ bsum, int nb) {
  __shared__ int ts[512];
  int tid = threadIdx.x;
  int v = (tid < nb) ? bsum[tid] : 0;
  ts[tid] = v;
  __syncthreads();
  for (int off = 1; off < 512; off <<= 1) {
    int t = (tid >= off) ? ts[tid - off] : 0;
    __syncthreads();
    ts[tid] += t;
    __syncthreads();
  }
  if (tid < nb) bsum[tid] = ts[tid] - v;  // exclusive
}

__global__ __launch_bounds__(256) void scan3_k(int* __restrict__ offs,
                                               int* __restrict__ cur,
                                               const int* __restrict__ bsum,
                                               int n, int total) {
  int base = blockIdx.x * 1024 + threadIdx.x * 4;
  int add = bsum[blockIdx.x];
#pragma unroll
  for (int i = 0; i < 4; ++i) {
    int idx = base + i;
    if (idx < n) {
      int t = offs[idx] + add;
      offs[idx] = t;
      cur[idx] = t;
    }
  }
  if (blockIdx.x == 0 && threadIdx.x == 0) offs[n] = total;
}

__global__ __launch_bounds__(256) void place_k(const int* __restrict__ row,
                                               const int* __restrict__ col,
                                               int* __restrict__ cur,
                                               int* __restrict__ srcs, int E) {
  int e = blockIdx.x * 256 + threadIdx.x;
  if (e < E) {
    int c = col[e];
    int p = atomicAdd(&cur[c], 1);
    srcs[p] = row[e];
  }
}

// ---- gathers ----
// GCN=true : out[c*ldo+d] = dv[c] * (dv[c]*x[c][d] + sum_r dv[r]*x[r][d])
// GCN=false: out[c*ldo+d] = dv[c] * sum_r x[r][d]           (dv = 1/cnt -> mean)
template <int DD, bool GCN>
__global__ __launch_bounds__(256) void gather_k(
    const float* __restrict__ x, const float* __restrict__ dv,
    const int* __restrict__ offs, const int* __restrict__ srcs,
    float* __restrict__ out, int ldo, int n) {
  constexpr int NPB = 256 / DD;
  int c = blockIdx.x * NPB + threadIdx.x / DD;
  int d = threadIdx.x & (DD - 1);
  if (c >= n) return;
  int s = offs[c], e = offs[c + 1];
  float acc = GCN ? dv[c] * x[(size_t)c * DD + d] : 0.f;
  for (int k = s; k < e; ++k) {
    int r = srcs[k];
    float w = GCN ? dv[r] : 1.f;
    acc += w * x[(size_t)r * DD + d];
  }
  out[(size_t)c * ldo + d] = dv[c] * acc;
}

// out_l[c*128+d] = dll[c]*(dll[c]*t[c][d] + sum_ll dll[r]*t[r][d]) + bias[d]
__global__ __launch_bounds__(256) void gather_out_l_k(
    const float* __restrict__ t, const float* __restrict__ dll,
    const int* __restrict__ offs, const int* __restrict__ srcs,
    const float* __restrict__ bias, float* __restrict__ out, int n) {
  int c = blockIdx.x * 4 + threadIdx.x / 64;
  int d = threadIdx.x & 63;
  if (c >= n) return;
  float dc = dll[c];
  float acc = dc * t[(size_t)c * 64 + d];
  int s = offs[c], e = offs[c + 1];
  for (int k = s; k < e; ++k) {
    int r = srcs[k];
    acc += dll[r] * t[(size_t)r * 64 + d];
  }
  out[(size_t)c * 128 + d] = dc * acc + bias[d];
}

// out_p[c*128+d] = v[c][d] + dpp[c]*(dpp[c]*wp[c][d] + sum_pp dpp[r]*wp[r][d])
//                + ic[c]*sum_lp u[r][d] + b1[d] + b2[d]
__global__ __launch_bounds__(256) void gather_out_p_k(
    const float* __restrict__ wp, const float* __restrict__ u,
    const float* __restrict__ v, const float* __restrict__ dpp,
    const float* __restrict__ ic, const int* __restrict__ offs_pp,
    const int* __restrict__ offs_lp, const int* __restrict__ srcs,
    const float* __restrict__ b1, const float* __restrict__ b2,
    float* __restrict__ out, int n) {
  int c = blockIdx.x * 4 + threadIdx.x / 64;
  int d = threadIdx.x & 63;
  if (c >= n) return;
  float dc = dpp[c];
  float a1 = dc * wp[(size_t)c * 64 + d];
  for (int k = offs_pp[c]; k < offs_pp[c + 1]; ++k) {
    int r = srcs[k];
    a1 += dpp[r] * wp[(size_t)r * 64 + d];
  }
  float a2 = 0.f;
  for (int k = offs_lp[c]; k < offs_lp[c + 1]; ++k) {
    int r = srcs[k];
    a2 += u[(size_t)r * 64 + d];
  }
  out[(size_t)c * 128 + d] = v[(size_t)c * 64 + d] + dc * a1 + ic[c] * a2
                           + b1[d] + b2[d];
}

// ---- f32 register-tiled GEMM: C = (ACCUM?C:0) + A[n,128]@W[128,OC] (+bias)(relu) ----
#define KC 32
#define BM 128
template <int OC, bool ACCUM, bool RELU>
__global__ __launch_bounds__(256) void gemm_k(
    const float* __restrict__ A, const float* __restrict__ W,
    const float* __restrict__ bias, float* __restrict__ C, int n) {
  constexpr int TN = (OC == 128) ? 8 : 4;
  __shared__ float As[KC][BM + 4];
  __shared__ float Ws[KC][OC];

  const int tid = threadIdx.x;
  const int tr = tid >> 4;
  const int tc = tid & 15;
  const int row0 = blockIdx.x * BM;

  float acc[8][TN];
#pragma unroll
  for (int i = 0; i < 8; ++i)
#pragma unroll
    for (int j = 0; j < TN; ++j) acc[i][j] = 0.f;

  for (int kc = 0; kc < 128; kc += KC) {
    {
      int kk = tid & 31;
      int rr = tid >> 5;
#pragma unroll
      for (int p = 0; p < 16; ++p) {
        int r = rr + p * 8;
        int gr = row0 + r;
        As[kk][r] = (gr < n) ? A[(size_t)gr * 128 + kc + kk] : 0.f;
      }
    }
    for (int idx = tid; idx < KC * OC; idx += 256) {
      int kk = idx / OC, c = idx % OC;
      Ws[kk][c] = W[(size_t)(kc + kk) * OC + c];
    }
    __syncthreads();

#pragma unroll
    for (int k = 0; k < KC; ++k) {
      float4 a0 = *reinterpret_cast<const float4*>(&As[k][tr * 8]);
      float4 a1 = *reinterpret_cast<const float4*>(&As[k][tr * 8 + 4]);
      float a[8] = {a0.x, a0.y, a0.z, a0.w, a1.x, a1.y, a1.z, a1.w};
      float w[TN];
      if (TN == 8) {
        float4 w0 = *reinterpret_cast<const float4*>(&Ws[k][tc * TN]);
        float4 w1 = *reinterpret_cast<const float4*>(&Ws[k][tc * TN + 4]);
        w[0] = w0.x; w[1] = w0.y; w[2] = w0.z; w[3] = w0.w;
        w[4] = w1.x; w[5] = w1.y; w[6] = w1.z; w[7] = w1.w;
      } else {
        float4 w0 = *reinterpret_cast<const float4*>(&Ws[k][tc * TN]);
        w[0] = w0.x; w[1] = w0.y; w[2] = w0.z; w[3] = w0.w;
      }
#pragma unroll
      for (int i = 0; i < 8; ++i)
#pragma unroll
        for (int j = 0; j < TN; ++j) acc[i][j] += a[i] * w[j];
    }
    __syncthreads();
  }

#pragma unroll
  for (int i = 0; i < 8; ++i) {
    int gr = row0 + tr * 8 + i;
    if (gr < n) {
#pragma unroll
      for (int j = 0; j < TN; ++j) {
        int c = tc * TN + j;
        float v = acc[i][j];
        if (bias) v += bias[c];
        if (ACCUM) v += C[(size_t)gr * OC + c];
        if (RELU) v = fmaxf(v, 0.f);
        C[(size_t)gr * OC + c] = v;
      }
    }
  }
}

}  // namespace

extern "C" void kernel_launch(void* const* d_in, const int* in_sizes, int n_in,
                              void* d_out, int out_size, void* d_ws, size_t ws_size,
                              hipStream_t stream) {
  const size_t N = NN;
  const int E = EE;
  int* wsi = (int*)d_ws;
  float* wsf = (float*)d_ws;

  int* icnt = wsi;                       // 3N
  int* offs = wsi + 3 * N;               // 3N+1
  int* cur  = wsi + 6 * N + 4;           // 3N
  int* bsum = wsi + 9 * N + 4;           // 512
  float* dinv = wsf + 9 * N + 520;       // 3N  (dll | dpp | ic)
  int* srcs = wsi + 12 * N + 520;        // 3E
  const size_t FB = 12 * N + 520 + 3 * (size_t)E;  // %4 == 0
  float* buf0 = wsf + FB;
  float* buf1 = wsf + FB + 128 * N;
  float* h_l  = wsf + FB + 256 * N;
  float* h_p  = wsf + FB + 384 * N;
  float* dll = dinv;
  float* dpp = dinv + N;
  float* ic  = dinv + 2 * N;
  // layer-2 temps (alias agg buffers)
  float* t_l = buf0;
  float* u_  = buf0 + 64 * N;
  float* v_  = buf1;
  float* wp_ = buf1 + 64 * N;

  const int n3 = 3 * NN;
  const int NB = (n3 + 1023) / 1024;                // 293 scan blocks
  const int GRID_E = (E + 255) / 256;
  const int GRID_N = (NN + 255) / 256;
  const int GRID_GEMM = (NN + BM - 1) / BM;
  const int GRID_G128 = (NN + 1) / 2;               // 2 dst/block
  const int GRID_G64  = (NN + 3) / 4;               // 4 dst/block

  for (int g = 0; g < 2; ++g) {
    const int b = g * 19;
    const float* x_l   = (const float*)d_in[b + 0];
    const float* x_p   = (const float*)d_in[b + 1];
    const int*   ei_lp = (const int*)d_in[b + 2];
    const int*   ei_ll = (const int*)d_in[b + 3];
    const int*   ei_pp = (const int*)d_in[b + 4];
    const float* s1_wl = (const float*)d_in[b + 5];
    const float* s1_bl = (const float*)d_in[b + 6];
    const float* s1_wr = (const float*)d_in[b + 7];
    const float* ll1_w = (const float*)d_in[b + 8];
    const float* ll1_b = (const float*)d_in[b + 9];
    const float* pp1_w = (const float*)d_in[b + 10];
    const float* pp1_b = (const float*)d_in[b + 11];
    const float* s2_wl = (const float*)d_in[b + 12];
    const float* s2_bl = (const float*)d_in[b + 13];
    const float* s2_wr = (const float*)d_in[b + 14];
    const float* ll2_w = (const float*)d_in[b + 15];
    const float* ll2_b = (const float*)d_in[b + 16];
    const float* pp2_w = (const float*)d_in[b + 17];
    const float* pp2_b = (const float*)d_in[b + 18];
    float* out_l = (float*)d_out + g * 64;
    float* out_p = (float*)d_out + 128 * N + g * 64;

    // --- CSR build: counts -> scan (concatenated ll|pp|lp) -> place ---
    zero_int_k<<<(n3 + 255) / 256, 256, 0, stream>>>(icnt, n3);
    count_int_k<<<GRID_E, 256, 0, stream>>>(ei_ll + E, icnt, E);
    count_int_k<<<GRID_E, 256, 0, stream>>>(ei_pp + E, icnt + N, E);
    count_int_k<<<GRID_E, 256, 0, stream>>>(ei_lp + E, icnt + 2 * N, E);
    make_inv_k<<<GRID_N, 256, 0, stream>>>(icnt, icnt + N, icnt + 2 * N,
                                           dll, dpp, ic, NN);
    scan1_k<<<NB, 256, 0, stream>>>(icnt, offs, bsum, n3);
    scan2_k<<<1, 512, 0, stream>>>(bsum, NB);
    scan3_k<<<NB, 256, 0, stream>>>(offs, cur, bsum, n3, 3 * E);
    place_k<<<GRID_E, 256, 0, stream>>>(ei_ll, ei_ll + E, cur, srcs, E);
    place_k<<<GRID_E, 256, 0, stream>>>(ei_pp, ei_pp + E, cur + N, srcs, E);
    place_k<<<GRID_E, 256, 0, stream>>>(ei_lp, ei_lp + E, cur + 2 * N, srcs, E);

    // --- layer 1 ---
    // h_l = relu(GCN_ll(x_l) @ ll1_w + ll1_b)
    gather_k<128, true><<<GRID_G128, 256, 0, stream>>>(x_l, dll, offs, srcs,
                                                       buf0, 128, NN);
    gemm_k<128, false, true><<<GRID_GEMM, 256, 0, stream>>>(buf0, ll1_w, ll1_b,
                                                            h_l, NN);
    // h_p = relu(x_p@s1_wr + s1_bl + GCN_pp(x_p)@pp1_w + pp1_b + mean_lp(x_l)@s1_wl)
    gemm_k<128, false, false><<<GRID_GEMM, 256, 0, stream>>>(x_p, s1_wr, s1_bl,
                                                             h_p, NN);
    gather_k<128, true><<<GRID_G128, 256, 0, stream>>>(x_p, dpp, offs + N, srcs,
                                                       buf1, 128, NN);
    gemm_k<128, true, false><<<GRID_GEMM, 256, 0, stream>>>(buf1, pp1_w, pp1_b,
                                                            h_p, NN);
    gather_k<128, false><<<GRID_G128, 256, 0, stream>>>(x_l, ic, offs + 2 * N,
                                                        srcs, buf1, 128, NN);
    gemm_k<128, true, true><<<GRID_GEMM, 256, 0, stream>>>(buf1, s1_wl, nullptr,
                                                           h_p, NN);

    // --- layer 2: project to 64 first, then aggregate ---
    gemm_k<64, false, false><<<GRID_GEMM, 256, 0, stream>>>(h_l, ll2_w, nullptr,
                                                            t_l, NN);
    gemm_k<64, false, false><<<GRID_GEMM, 256, 0, stream>>>(h_l, s2_wl, nullptr,
                                                            u_, NN);
    gemm_k<64, false, false><<<GRID_GEMM, 256, 0, stream>>>(h_p, s2_wr, nullptr,
                                                            v_, NN);
    gemm_k<64, false, false><<<GRID_GEMM, 256, 0, stream>>>(h_p, pp2_w, nullptr,
                                                            wp_, NN);
    gather_out_l_k<<<GRID_G64, 256, 0, stream>>>(t_l, dll, offs, srcs, ll2_b,
                                                 out_l, NN);
    gather_out_p_k<<<GRID_G64, 256, 0, stream>>>(wp_, u_, v_, dpp, ic,
                                                 offs + N, offs + 2 * N, srcs,
                                                 s2_bl, pp2_b, out_p, NN);
  }
  (void)in_sizes; (void)n_in; (void)out_size; (void)ws_size;
}

// Round 4
// 1857.591 us; speedup vs baseline: 2.1863x; 1.8887x over previous
//
#include <hip/hip_runtime.h>

// HeteroGNN r4: CSR gathers (bf16 out) + fused bf16-MFMA GEMMs.
// N=100000, E=500000, D_IN=D_HID=128, D_OUT=64.
//
// ws layout (32-bit words), FB = 12N+520+3E = 2,700,520:
//   icnt[0,3N) offs[3N,6N+1) cur[6N+4,9N+4) bsum[9N+4,9N+516)
//   dinv[9N+520,12N+520)  srcs[12N+520,FB)
//   FB+0      : agg_ll_bf (N*128 bf16 = 6.4M words)   } aliased later by
//   FB+6.4M   : agg_pp_bf                             }  TU f32 (N*128)
//   FB+12.8M  : agg_lp_bf                             } aliased later by
//   FB+19.2M  : xp_bf                                 }  VW f32 (N*128)
//   FB+25.6M  : h_l_bf     FB+32.0M : h_p_bf
//   FB+38.4M  : WT (6 x 128x128 bf16 = 49152 words)
// Total ~ 165 MB.

namespace {

constexpr int NN = 100000;
constexpr int EE = 500000;

typedef __attribute__((ext_vector_type(8))) short short8;
typedef __attribute__((ext_vector_type(4))) float f32x4;

__device__ inline ushort f2bf(float f) {
  union { float f; unsigned u; } v; v.f = f;
  unsigned r = v.u + 0x7FFFu + ((v.u >> 16) & 1u);
  return (ushort)(r >> 16);
}

__global__ __launch_bounds__(256) void zero_int_k(int* __restrict__ p, int n) {
  int i = blockIdx.x * 256 + threadIdx.x;
  if (i < n) p[i] = 0;
}

__global__ __launch_bounds__(256) void count_int_k(const int* __restrict__ col,
                                                   int* __restrict__ cnt, int E) {
  int i = blockIdx.x * 256 + threadIdx.x;
  if (i < E) atomicAdd(&cnt[col[i]], 1);
}

__global__ __launch_bounds__(256) void make_inv_k(
    const int* __restrict__ cll, const int* __restrict__ cpp,
    const int* __restrict__ clp, float* __restrict__ dll,
    float* __restrict__ dpp, float* __restrict__ ic, int n) {
  int i = blockIdx.x * 256 + threadIdx.x;
  if (i < n) {
    dll[i] = rsqrtf((float)cll[i] + 1.0f);
    dpp[i] = rsqrtf((float)cpp[i] + 1.0f);
    ic[i]  = 1.0f / fmaxf((float)clp[i], 1.0f);
  }
}

// ---- 3-kernel exclusive scan (1024 elems/block) ----
__global__ __launch_bounds__(256) void scan1_k(const int* __restrict__ cnt,
                                               int* __restrict__ offs,
                                               int* __restrict__ bsum, int n) {
  __shared__ int ts[256];
  int tid = threadIdx.x;
  int base = blockIdx.x * 1024 + tid * 4;
  int v[4];
#pragma unroll
  for (int i = 0; i < 4; ++i) v[i] = (base + i < n) ? cnt[base + i] : 0;
  int s = v[0] + v[1] + v[2] + v[3];
  ts[tid] = s;
  __syncthreads();
  for (int off = 1; off < 256; off <<= 1) {
    int t = (tid >= off) ? ts[tid - off] : 0;
    __syncthreads();
    ts[tid] += t;
    __syncthreads();
  }
  int run = ts[tid] - s;
#pragma unroll
  for (int i = 0; i < 4; ++i) {
    if (base + i < n) offs[base + i] = run;
    run += v[i];
  }
  if (tid == 255) bsum[blockIdx.x] = ts[255];
}

__global__ __launch_bounds__(512) void scan2_k(int* __restrict__ bsum, int nb) {
  __shared__ int ts[512];
  int tid = threadIdx.x;
  int v = (tid < nb) ? bsum[tid] : 0;
  ts[tid] = v;
  __syncthreads();
  for (int off = 1; off < 512; off <<= 1) {
    int t = (tid >= off) ? ts[tid - off] : 0;
    __syncthreads();
    ts[tid] += t;
    __syncthreads();
  }
  if (tid < nb) bsum[tid] = ts[tid] - v;
}

__global__ __launch_bounds__(256) void scan3_k(int* __restrict__ offs,
                                               int* __restrict__ cur,
                                               const int* __restrict__ bsum,
                                               int n, int total) {
  int base = blockIdx.x * 1024 + threadIdx.x * 4;
  int add = bsum[blockIdx.x];
#pragma unroll
  for (int i = 0; i < 4; ++i) {
    int idx = base + i;
    if (idx < n) {
      int t = offs[idx] + add;
      offs[idx] = t;
      cur[idx] = t;
    }
  }
  if (blockIdx.x == 0 && threadIdx.x == 0) offs[n] = total;
}

__global__ __launch_bounds__(256) void place_k(const int* __restrict__ row,
                                               const int* __restrict__ col,
                                               int* __restrict__ cur,
                                               int* __restrict__ srcs, int E) {
  int e = blockIdx.x * 256 + threadIdx.x;
  if (e < E) {
    int c = col[e];
    int p = atomicAdd(&cur[c], 1);
    srcs[p] = row[e];
  }
}

// ---- L1 gathers: f32 math, bf16 output ----
// GCN=true : out = dv[c]*(dv[c]*x[c] + sum dv[r]*x[r]);  GCN=false: dv[c]*sum x[r]
template <bool GCN>
__global__ __launch_bounds__(256) void gather_bf_k(
    const float* __restrict__ x, const float* __restrict__ dv,
    const int* __restrict__ offs, const int* __restrict__ srcs,
    ushort* __restrict__ out, int n) {
  int c = blockIdx.x * 2 + (threadIdx.x >> 7);
  int d = threadIdx.x & 127;
  if (c >= n) return;
  int s = offs[c], e = offs[c + 1];
  float acc = GCN ? dv[c] * x[(size_t)c * 128 + d] : 0.f;
  for (int k = s; k < e; ++k) {
    int r = srcs[k];
    float w = GCN ? dv[r] : 1.f;
    acc += w * x[(size_t)r * 128 + d];
  }
  out[(size_t)c * 128 + d] = f2bf(dv[c] * acc);
}

__global__ __launch_bounds__(256) void conv_bf_k(const float* __restrict__ in,
                                                 ushort* __restrict__ out, int n4) {
  int i = blockIdx.x * 256 + threadIdx.x;
  if (i < n4) {
    float4 v = reinterpret_cast<const float4*>(in)[i];
    ushort4 o;
    o.x = f2bf(v.x); o.y = f2bf(v.y); o.z = f2bf(v.z); o.w = f2bf(v.w);
    reinterpret_cast<ushort4*>(out)[i] = o;
  }
}

// ---- weight prep: WT[n][k] = bf16(W[k][n]); 6 blocks of 128x128 ----
__global__ __launch_bounds__(256) void prep_w_k(
    const float* __restrict__ ll1_w, const float* __restrict__ s1_wr,
    const float* __restrict__ pp1_w, const float* __restrict__ s1_wl,
    const float* __restrict__ ll2_w, const float* __restrict__ s2_wl,
    const float* __restrict__ s2_wr, const float* __restrict__ pp2_w,
    ushort* __restrict__ wt) {
  int idx = blockIdx.x * 256 + threadIdx.x;
  if (idx >= 6 * 16384) return;
  int blk = idx >> 14, r = idx & 16383;
  int n = r >> 7, k = r & 127;
  float v;
  switch (blk) {
    case 0: v = ll1_w[k * 128 + n]; break;
    case 1: v = s1_wr[k * 128 + n]; break;
    case 2: v = pp1_w[k * 128 + n]; break;
    case 3: v = s1_wl[k * 128 + n]; break;
    case 4: v = (n < 64) ? ll2_w[k * 64 + n] : s2_wl[k * 64 + (n - 64)]; break;
    default: v = (n < 64) ? s2_wr[k * 64 + n] : pp2_w[k * 64 + (n - 64)]; break;
  }
  wt[idx] = f2bf(v);
}

// ---- fused bf16 MFMA GEMM: out[n,128] = sum_i A_i[n,128] @ W_i (+b0+b1)(relu) ----
// 256 thr = 4 waves; wave owns 32 rows x 128 cols (2 m-frags x 8 n-frags).
// B staged in LDS as WT[n][k] bf16 with XOR swizzle (k ^ ((n&7)<<3)).
template <int NA, bool RELU, bool OUTBF16>
__global__ __launch_bounds__(256) void mfma_gemm_k(
    const ushort* __restrict__ a0, const ushort* __restrict__ a1,
    const ushort* __restrict__ a2,
    const ushort* __restrict__ w0, const ushort* __restrict__ w1,
    const ushort* __restrict__ w2,
    const float* __restrict__ b0, const float* __restrict__ b1,
    void* __restrict__ outp, int nrows) {
  __shared__ ushort wt[128 * 128];
  const int tid = threadIdx.x;
  const int wv  = tid >> 6;
  const int ln  = tid & 63;
  const int lr  = ln & 15;   // frag row (A) / col (B, D)
  const int lg  = ln >> 4;   // k-group
  const int row0 = blockIdx.x * 128 + wv * 32;

  f32x4 acc[2][8];
#pragma unroll
  for (int mi = 0; mi < 2; ++mi)
#pragma unroll
    for (int ni = 0; ni < 8; ++ni) acc[mi][ni] = (f32x4){0.f, 0.f, 0.f, 0.f};

  const ushort* As[3] = {a0, a1, a2};
  const ushort* Ws[3] = {w0, w1, w2};

#pragma unroll
  for (int ai = 0; ai < NA; ++ai) {
    if (ai) __syncthreads();
    const ushort* wg = Ws[ai];
#pragma unroll
    for (int i = 0; i < 8; ++i) {
      int c = tid + i * 256;          // 2048 chunks of 8 ushorts
      int r = c >> 4, cc = c & 15;
      short8 v = *reinterpret_cast<const short8*>(wg + r * 128 + cc * 8);
      int di = r * 128 + ((cc * 8) ^ ((r & 7) << 3));
      *reinterpret_cast<short8*>(&wt[di]) = v;
    }
    __syncthreads();
    const ushort* Ag = As[ai];
#pragma unroll
    for (int ks = 0; ks < 4; ++ks) {
      int k0 = ks * 32 + lg * 8;
      short8 afr[2];
#pragma unroll
      for (int mi = 0; mi < 2; ++mi) {
        size_t r = (size_t)(row0 + mi * 16 + lr);
        afr[mi] = *reinterpret_cast<const short8*>(Ag + r * 128 + k0);
      }
#pragma unroll
      for (int ni = 0; ni < 8; ++ni) {
        int n = ni * 16 + lr;
        int bi = n * 128 + (k0 ^ ((n & 7) << 3));
        short8 bfr = *reinterpret_cast<const short8*>(&wt[bi]);
#pragma unroll
        for (int mi = 0; mi < 2; ++mi)
          acc[mi][ni] = __builtin_amdgcn_mfma_f32_16x16x32_bf16(
              afr[mi], bfr, acc[mi][ni], 0, 0, 0);
      }
    }
  }

#pragma unroll
  for (int ni = 0; ni < 8; ++ni) {
    int col = ni * 16 + lr;
    float bb = 0.f;
    if (b0) bb += b0[col];
    if (b1) bb += b1[col];
#pragma unroll
    for (int mi = 0; mi < 2; ++mi) {
#pragma unroll
      for (int rg = 0; rg < 4; ++rg) {
        int row = row0 + mi * 16 + lg * 4 + rg;
        if (row < nrows) {
          float v = acc[mi][ni][rg] + bb;
          if (RELU) v = fmaxf(v, 0.f);
          if (OUTBF16)
            ((ushort*)outp)[(size_t)row * 128 + col] = f2bf(v);
          else
            ((float*)outp)[(size_t)row * 128 + col] = v;
        }
      }
    }
  }
}

// ---- final gathers (f32 in, f32 out into concat layout) ----
// out_l[c][d] = dll[c]*(dll[c]*TU[c][d] + sum_ll dll[r]*TU[r][d]) + ll2_b[d]
__global__ __launch_bounds__(256) void gather_out_l_k(
    const float* __restrict__ TU, const float* __restrict__ dll,
    const int* __restrict__ offs, const int* __restrict__ srcs,
    const float* __restrict__ bias, float* __restrict__ out, int n) {
  int c = blockIdx.x * 4 + (threadIdx.x >> 6);
  int d = threadIdx.x & 63;
  if (c >= n) return;
  float dc = dll[c];
  float acc = dc * TU[(size_t)c * 128 + d];
  int s = offs[c], e = offs[c + 1];
  for (int k = s; k < e; ++k) {
    int r = srcs[k];
    acc += dll[r] * TU[(size_t)r * 128 + d];
  }
  out[(size_t)c * 128 + d] = dc * acc + bias[d];
}

// out_p[c][d] = VW[c][d] + dpp[c]*(dpp[c]*VW[c][64+d] + sum_pp dpp[r]*VW[r][64+d])
//             + ic[c]*sum_lp TU[r][64+d] + b1[d] + b2[d]
__global__ __launch_bounds__(256) void gather_out_p_k(
    const float* __restrict__ TU, const float* __restrict__ VW,
    const float* __restrict__ dpp, const float* __restrict__ ic,
    const int* __restrict__ offs_pp, const int* __restrict__ offs_lp,
    const int* __restrict__ srcs, const float* __restrict__ b1,
    const float* __restrict__ b2, float* __restrict__ out, int n) {
  int c = blockIdx.x * 4 + (threadIdx.x >> 6);
  int d = threadIdx.x & 63;
  if (c >= n) return;
  float dc = dpp[c];
  float a1 = dc * VW[(size_t)c * 128 + 64 + d];
  for (int k = offs_pp[c]; k < offs_pp[c + 1]; ++k) {
    int r = srcs[k];
    a1 += dpp[r] * VW[(size_t)r * 128 + 64 + d];
  }
  float a2 = 0.f;
  for (int k = offs_lp[c]; k < offs_lp[c + 1]; ++k) {
    int r = srcs[k];
    a2 += TU[(size_t)r * 128 + 64 + d];
  }
  out[(size_t)c * 128 + d] = VW[(size_t)c * 128 + d] + dc * a1 + ic[c] * a2
                           + b1[d] + b2[d];
}

}  // namespace

extern "C" void kernel_launch(void* const* d_in, const int* in_sizes, int n_in,
                              void* d_out, int out_size, void* d_ws, size_t ws_size,
                              hipStream_t stream) {
  const size_t N = NN;
  const int E = EE;
  int* wsi = (int*)d_ws;
  float* wsf = (float*)d_ws;

  int* icnt = wsi;
  int* offs = wsi + 3 * N;
  int* cur  = wsi + 6 * N + 4;
  int* bsum = wsi + 9 * N + 4;
  float* dinv = wsf + 9 * N + 520;
  int* srcs = wsi + 12 * N + 520;
  const size_t FB = 12 * N + 520 + 3 * (size_t)E;   // words; %4==0
  const size_t WB = (size_t)N * 64;                 // words per N*128 bf16 buf

  ushort* agg_ll_bf = (ushort*)(wsf + FB);
  ushort* agg_pp_bf = (ushort*)(wsf + FB + WB);
  ushort* agg_lp_bf = (ushort*)(wsf + FB + 2 * WB);
  ushort* xp_bf     = (ushort*)(wsf + FB + 3 * WB);
  float*  TU        = wsf + FB;                 // aliases agg_ll+agg_pp
  float*  VW        = wsf + FB + 2 * WB;        // aliases agg_lp+xp_bf
  ushort* h_l_bf    = (ushort*)(wsf + FB + 4 * WB);
  ushort* h_p_bf    = (ushort*)(wsf + FB + 5 * WB);
  ushort* WT        = (ushort*)(wsf + FB + 6 * WB);   // 6*16384 ushorts

  float* dll = dinv;
  float* dpp = dinv + N;
  float* ic  = dinv + 2 * N;

  const int n3 = 3 * NN;
  const int NB = (n3 + 1023) / 1024;
  const int GRID_E = (E + 255) / 256;
  const int GRID_N = (NN + 255) / 256;
  const int GRID_MM = (NN + 127) / 128;         // 782
  const int GRID_G128 = (NN + 1) / 2;
  const int GRID_G64  = (NN + 3) / 4;
  const int GRID_CONV = (NN * 128 / 4 + 255) / 256;

  for (int g = 0; g < 2; ++g) {
    const int b = g * 19;
    const float* x_l   = (const float*)d_in[b + 0];
    const float* x_p   = (const float*)d_in[b + 1];
    const int*   ei_lp = (const int*)d_in[b + 2];
    const int*   ei_ll = (const int*)d_in[b + 3];
    const int*   ei_pp = (const int*)d_in[b + 4];
    const float* s1_wl = (const float*)d_in[b + 5];
    const float* s1_bl = (const float*)d_in[b + 6];
    const float* s1_wr = (const float*)d_in[b + 7];
    const float* ll1_w = (const float*)d_in[b + 8];
    const float* ll1_b = (const float*)d_in[b + 9];
    const float* pp1_w = (const float*)d_in[b + 10];
    const float* pp1_b = (const float*)d_in[b + 11];
    const float* s2_wl = (const float*)d_in[b + 12];
    const float* s2_bl = (const float*)d_in[b + 13];
    const float* s2_wr = (const float*)d_in[b + 14];
    const float* ll2_w = (const float*)d_in[b + 15];
    const float* ll2_b = (const float*)d_in[b + 16];
    const float* pp2_w = (const float*)d_in[b + 17];
    const float* pp2_b = (const float*)d_in[b + 18];
    float* out_l = (float*)d_out + g * 64;
    float* out_p = (float*)d_out + 128 * N + g * 64;

    // --- CSR build ---
    zero_int_k<<<(n3 + 255) / 256, 256, 0, stream>>>(icnt, n3);
    count_int_k<<<GRID_E, 256, 0, stream>>>(ei_ll + E, icnt, E);
    count_int_k<<<GRID_E, 256, 0, stream>>>(ei_pp + E, icnt + N, E);
    count_int_k<<<GRID_E, 256, 0, stream>>>(ei_lp + E, icnt + 2 * N, E);
    make_inv_k<<<GRID_N, 256, 0, stream>>>(icnt, icnt + N, icnt + 2 * N,
                                           dll, dpp, ic, NN);
    scan1_k<<<NB, 256, 0, stream>>>(icnt, offs, bsum, n3);
    scan2_k<<<1, 512, 0, stream>>>(bsum, NB);
    scan3_k<<<NB, 256, 0, stream>>>(offs, cur, bsum, n3, 3 * E);
    place_k<<<GRID_E, 256, 0, stream>>>(ei_ll, ei_ll + E, cur, srcs, E);
    place_k<<<GRID_E, 256, 0, stream>>>(ei_pp, ei_pp + E, cur + N, srcs, E);
    place_k<<<GRID_E, 256, 0, stream>>>(ei_lp, ei_lp + E, cur + 2 * N, srcs, E);

    // --- weight prep + input converts ---
    prep_w_k<<<(6 * 16384 + 255) / 256, 256, 0, stream>>>(
        ll1_w, s1_wr, pp1_w, s1_wl, ll2_w, s2_wl, s2_wr, pp2_w, WT);
    conv_bf_k<<<GRID_CONV, 256, 0, stream>>>(x_p, xp_bf, NN * 32);

    // --- layer 1 aggregation (bf16 out) ---
    gather_bf_k<true><<<GRID_G128, 256, 0, stream>>>(x_l, dll, offs, srcs,
                                                     agg_ll_bf, NN);
    gather_bf_k<true><<<GRID_G128, 256, 0, stream>>>(x_p, dpp, offs + N, srcs,
                                                     agg_pp_bf, NN);
    gather_bf_k<false><<<GRID_G128, 256, 0, stream>>>(x_l, ic, offs + 2 * N, srcs,
                                                      agg_lp_bf, NN);

    // --- layer 1 GEMMs (MFMA) ---
    mfma_gemm_k<1, true, true><<<GRID_MM, 256, 0, stream>>>(
        agg_ll_bf, nullptr, nullptr, WT, nullptr, nullptr,
        ll1_b, nullptr, h_l_bf, NN);
    mfma_gemm_k<3, true, true><<<GRID_MM, 256, 0, stream>>>(
        xp_bf, agg_pp_bf, agg_lp_bf, WT + 16384, WT + 2 * 16384, WT + 3 * 16384,
        s1_bl, pp1_b, h_p_bf, NN);

    // --- layer 2 GEMMs (project to 64+64, then aggregate) ---
    mfma_gemm_k<1, false, false><<<GRID_MM, 256, 0, stream>>>(
        h_l_bf, nullptr, nullptr, WT + 4 * 16384, nullptr, nullptr,
        nullptr, nullptr, TU, NN);
    mfma_gemm_k<1, false, false><<<GRID_MM, 256, 0, stream>>>(
        h_p_bf, nullptr, nullptr, WT + 5 * 16384, nullptr, nullptr,
        nullptr, nullptr, VW, NN);

    // --- layer 2 aggregation straight into output ---
    gather_out_l_k<<<GRID_G64, 256, 0, stream>>>(TU, dll, offs, srcs, ll2_b,
                                                 out_l, NN);
    gather_out_p_k<<<GRID_G64, 256, 0, stream>>>(TU, VW, dpp, ic, offs + N,
                                                 offs + 2 * N, srcs, s2_bl,
                                                 pp2_b, out_p, NN);
  }
  (void)in_sizes; (void)n_in; (void)out_size; (void)ws_size;
}